// Round 5
// baseline (1439.297 us; speedup 1.0000x reference)
//
#include <hip/hip_runtime.h>
#include <math.h>

// ---------------- problem constants ----------------
#define NB     64
#define SL     2048
#define NTOK   (NB*SL)
#define EMB_D  128
#define DMODEL 128
#define DIN    256
#define DST    16
#define NLAYER 4
#define SEG    64
#define NSEG   (SL/SEG)        // 32
#define L2E    1.4426950408889634f
#define LN2    0.6931471805599453f

typedef __bf16 bf16x8 __attribute__((ext_vector_type(8)));
typedef __bf16 bf16x4 __attribute__((ext_vector_type(4)));
typedef float  f32x4  __attribute__((ext_vector_type(4)));
typedef float  f32x2  __attribute__((ext_vector_type(2)));

// fixed small region (floats)
#define FIX_PL   ((size_t)0)
#define FIX_PM   (FIX_PL + 131072)
#define FIX_PD   (FIX_PM + 1024)
#define FIX_H1   (FIX_PD + 8192)
#define FIX_H2   (FIX_H1 + 32768)
#define FIX_WP   (FIX_H2 + 32768)
#define FIX_W2B  (FIX_WP + 65536)
#define FIX_WINB (FIX_W2B + 24576)
#define FIX_WOUTB (FIX_WINB + 131072)
#define FIX_END  (FIX_WOUTB + 65536)

// raw-instruction transcendentals
__device__ __forceinline__ float fexp2(float x){ return __builtin_amdgcn_exp2f(x); }
__device__ __forceinline__ float flog2(float x){ return __builtin_amdgcn_logf(x); }
__device__ __forceinline__ float frcp (float x){ return __builtin_amdgcn_rcpf(x); }
__device__ __forceinline__ float fast_exp(float x){ return fexp2(x*L2E); }
__device__ __forceinline__ float siluf(float v){ return v * frcp(1.f + fast_exp(-v)); }
__device__ __forceinline__ float softplusf(float a){
  return fmaxf(a,0.f) + flog2(1.f + fexp2(-fabsf(a)*L2E)) * LN2;
}
__device__ __forceinline__ unsigned short bfbits(float x){
  __bf16 b = (__bf16)x; return __builtin_bit_cast(unsigned short, b);
}
__device__ __forceinline__ unsigned int packdu(float dt, float hi){
  return ((unsigned int)bfbits(hi) << 16) | (unsigned int)bfbits(dt);
}

// packed f32 helpers (target: v_pk_fma_f32 / v_pk_mul_f32)
__device__ __forceinline__ f32x2 pkfma(f32x2 a, f32x2 b, f32x2 c){
#if __has_builtin(__builtin_elementwise_fma)
  return __builtin_elementwise_fma(a, b, c);
#else
  return (f32x2){ fmaf(a.x,b.x,c.x), fmaf(a.y,b.y,c.y) };
#endif
}

// ---------------- weight prep ----------------
__global__ void k_w2b(const float* __restrict__ cw, __bf16* __restrict__ w2){
  int g = blockIdx.x*256 + threadIdx.x;
  if (g >= 128*384) return;
  int d = g / 384, j = g % 384;
  int k = j >> 7, e = j & 127;
  w2[d*384 + k*128 + e] = (__bf16)cw[d*384 + e*3 + k];
}

__global__ void k_cvt(const float* __restrict__ src, __bf16* __restrict__ dst, int n){
  int i = blockIdx.x*256 + threadIdx.x;
  if (i < n) dst[i] = (__bf16)src[i];
}

// identity map: rows 0..7 dt, 8..23 B, 24..39 C (deinterleaved), 40..63 zero
__global__ void k_wprep(const float* __restrict__ xpw, __bf16* __restrict__ wp){
  int g = blockIdx.x*256 + threadIdx.x;      // 65536
  int l = g >> 14, rem = g & 16383;
  int n = rem >> 8, k = rem & 255;
  float v = (n < 40) ? xpw[(size_t)l*40*256 + n*256 + k] : 0.f;
  wp[g] = (__bf16)v;
}

// ---------------- rmsnorm scale only (after front conv) ----------------
__global__ __launch_bounds__(256) void k_rmsscale(const float* __restrict__ x,
                                                  float* __restrict__ rs){
  int wv = threadIdx.x>>6, lane = threadIdx.x&63;
  size_t tok = (size_t)blockIdx.x*4 + wv;
  float2 v = *(const float2*)(x + tok*128 + lane*2);
  float ss = v.x*v.x + v.y*v.y;
  #pragma unroll
  for (int m=1;m<64;m<<=1) ss += __shfl_xor(ss, m);
  float r = rsqrtf(ss*(1.f/128.f) + 1e-5f);
  if (lane == 0) rs[tok] = r;
}

// ---------------- bf16 MFMA GEMM ----------------
// MODE 0: A = inline embed+BN gather from tokens (Av=int* tokens, rsp=emb,
//         nwp=bn_w, bnbp=bn_b), epi relu(+conv bias) -> out fp32
// MODE 1: A fp32 (x), staged *rs*nw; epi n<256 -> outb (xi bf16), else outz (gz bf16)
template<int MODE, int K, int N>
__global__ __launch_bounds__(256) void k_mgemm(
    const void* __restrict__ Av, const __bf16* __restrict__ Wb,
    const float* __restrict__ bias, const float* __restrict__ rsp,
    const float* __restrict__ nwp, const float* __restrict__ bnbp,
    float* __restrict__ out, __bf16* __restrict__ outb, __bf16* __restrict__ outz){
  __shared__ __bf16 As[128][40];
  __shared__ __bf16 Bs[128][40];
  const int tid  = threadIdx.x;
  const int wave = tid >> 6;
  const int lane = tid & 63;
  const int col  = lane & 15;
  const int quad = lane >> 4;
  const int wm = (wave & 1) * 64;
  const int wn = (wave >> 1) * 64;
  const int m0 = blockIdx.y * 128;
  const int n0 = blockIdx.x * 128;

  f32x4 acc[4][4];
  #pragma unroll
  for (int i=0;i<4;i++)
    #pragma unroll
    for (int j=0;j<4;j++) acc[i][j] = (f32x4){0.f,0.f,0.f,0.f};

  const int sm = tid >> 3;
  const int sk4 = (tid & 7) * 4;
  const int bn = tid >> 2;
  const int bk8 = (tid & 3) * 8;

  for (int k0 = 0; k0 < K; k0 += 32){
    if constexpr(MODE==0){
      const int* tok = (const int*)Av;
      const int tap = k0 >> 7;
      const int e = (k0 & 127) + sk4;
      const float sc = rsqrtf(1.0f + 1e-5f);
      float4 bw4 = *(const float4*)(nwp + e);
      float4 bb4 = *(const float4*)(bnbp + e);
      float4 s4;
      s4.x = bw4.x*sc; s4.y = bw4.y*sc; s4.z = bw4.z*sc; s4.w = bw4.w*sc;
      #pragma unroll
      for (int p=0;p<4;p++){
        int m = p*32 + sm;
        int tokpos = m0 + m;
        int t = (tokpos & 2047) + tap - 1;
        float4 v = {0.f,0.f,0.f,0.f};
        if ((unsigned)t < 2048u){
          int id = tok[((size_t)(tokpos >> 11) << 11) + t];
          float4 ev = *(const float4*)(rsp + (size_t)id*EMB_D + e);
          v.x = fmaf(ev.x, s4.x, bb4.x);
          v.y = fmaf(ev.y, s4.y, bb4.y);
          v.z = fmaf(ev.z, s4.z, bb4.z);
          v.w = fmaf(ev.w, s4.w, bb4.w);
        }
        bf16x4 o;
        o[0] = (__bf16)v.x; o[1] = (__bf16)v.y; o[2] = (__bf16)v.z; o[3] = (__bf16)v.w;
        *(bf16x4*)&As[m][sk4] = o;
      }
    } else {
      const size_t abase = (size_t)m0 * K;
      #pragma unroll
      for (int p=0;p<4;p++){
        int m = p*32 + sm;
        const float* A = (const float*)Av;
        float4 x4 = *(const float4*)(A + abase + (size_t)m*K + k0 + sk4);
        float4 w4 = *(const float4*)(nwp + k0 + sk4);
        float s = rsp[m0 + m];
        float4 v;
        v.x = x4.x*s*w4.x; v.y = x4.y*s*w4.y; v.z = x4.z*s*w4.z; v.w = x4.w*s*w4.w;
        bf16x4 o;
        o[0] = (__bf16)v.x; o[1] = (__bf16)v.y; o[2] = (__bf16)v.z; o[3] = (__bf16)v.w;
        *(bf16x4*)&As[m][sk4] = o;
      }
    }
    #pragma unroll
    for (int p=0;p<2;p++){
      int n = p*64 + bn;
      bf16x8 w = *(const bf16x8*)(Wb + (size_t)(n0+n)*K + k0 + bk8);
      *(bf16x8*)&Bs[n][bk8] = w;
    }
    __syncthreads();
    bf16x8 af[4], bfr[4];
    const int fq = quad*8;
    #pragma unroll
    for (int i=0;i<4;i++) af[i]  = *(const bf16x8*)&As[wm + i*16 + col][fq];
    #pragma unroll
    for (int j=0;j<4;j++) bfr[j] = *(const bf16x8*)&Bs[wn + j*16 + col][fq];
    #pragma unroll
    for (int i=0;i<4;i++)
      #pragma unroll
      for (int j=0;j<4;j++)
        acc[i][j] = __builtin_amdgcn_mfma_f32_16x16x32_bf16(af[i], bfr[j], acc[i][j], 0, 0, 0);
    __syncthreads();
  }

  #pragma unroll
  for (int i=0;i<4;i++){
    #pragma unroll
    for (int j=0;j<4;j++){
      int n_l = wn + j*16 + col;
      #pragma unroll
      for (int r=0;r<4;r++){
        int m = m0 + wm + i*16 + quad*4 + r;
        float c = acc[i][j][r];
        if constexpr(MODE==0){
          int n = n0 + n_l;
          out[(size_t)m*DMODEL + n] = fmaxf(c + bias[n], 0.f);
        } else {
          int n = n0 + n_l;
          if (n < DIN) outb[(size_t)m*DIN + n]        = (__bf16)c;
          else         outz[(size_t)m*DIN + n - DIN]  = (__bf16)siluf(c);
        }
      }
    }
  }
}

// ---------------- fused segment front: dwconv+silu -> MFMA x_proj -> scanA + y_local ----
__global__ __launch_bounds__(256) void k_seg(const __bf16* __restrict__ xi,
    const __bf16* __restrict__ wpb,
    const float* __restrict__ cw, const float* __restrict__ cb,
    const float* __restrict__ dtw, const float* __restrict__ dtb,
    const float* __restrict__ alog, const float* __restrict__ Dpar,
    float* __restrict__ vbc, unsigned int* __restrict__ dub,
    float* __restrict__ cseg, float* __restrict__ sdtb){
  __shared__ __bf16 sxc[64][264];
  __shared__ float vls[64][68];
  const int tid = threadIdx.x;
  const size_t m0 = (size_t)blockIdx.x * 64;
  const int b = (int)(m0 >> 11);
  const int g = (int)((m0 >> 6) & (NSEG-1));
  const int seq0 = (int)(m0 & 2047);

  // ---- phase 0: depthwise conv(k=4, bf16 in) + silu, rolling window ----
  {
    const int c4 = (tid & 63) * 4;
    const int tw = tid >> 6;           // 0..3
    const int t0 = tw * 16;
    float wc[4][4];
    #pragma unroll
    for (int j=0;j<4;j++)
      #pragma unroll
      for (int k=0;k<4;k++) wc[j][k] = cw[(c4+j)*4 + k];
    float4 cb4 = *(const float4*)(cb + c4);
    bf16x4 zed;
    zed[0] = (__bf16)0.f; zed[1] = (__bf16)0.f; zed[2] = (__bf16)0.f; zed[3] = (__bf16)0.f;
    bf16x4 win[3];
    #pragma unroll
    for (int j=0;j<3;j++){
      int tr = t0 - 3 + j;
      win[j] = (seq0 + tr >= 0) ? *(const bf16x4*)(xi + (m0 + tr)*DIN + c4) : zed;
    }
    #pragma unroll
    for (int i=0;i<16;i++){
      int t = t0 + i;
      bf16x4 w3 = *(const bf16x4*)(xi + (m0 + t)*DIN + c4);
      float4 acc = cb4;
      #pragma unroll
      for (int k=0;k<3;k++){
        acc.x = fmaf(wc[0][k], (float)win[k][0], acc.x);
        acc.y = fmaf(wc[1][k], (float)win[k][1], acc.y);
        acc.z = fmaf(wc[2][k], (float)win[k][2], acc.z);
        acc.w = fmaf(wc[3][k], (float)win[k][3], acc.w);
      }
      acc.x = fmaf(wc[0][3], (float)w3[0], acc.x);
      acc.y = fmaf(wc[1][3], (float)w3[1], acc.y);
      acc.z = fmaf(wc[2][3], (float)w3[2], acc.z);
      acc.w = fmaf(wc[3][3], (float)w3[3], acc.w);
      bf16x4 o;
      o[0]=(__bf16)siluf(acc.x); o[1]=(__bf16)siluf(acc.y);
      o[2]=(__bf16)siluf(acc.z); o[3]=(__bf16)siluf(acc.w);
      *(bf16x4*)&sxc[t][c4] = o;
      win[0] = win[1]; win[1] = win[2]; win[2] = w3;
    }
  }
  __syncthreads();

  // ---- phase 1: MFMA vls[64][64] = sxc[64x256] @ wpb[64x256]^T ----
  {
    const int wave = tid >> 6, lane = tid & 63;
    const int col = lane & 15, quad = lane >> 4;
    const int wn = wave * 16;
    f32x4 acc[4];
    #pragma unroll
    for (int i=0;i<4;i++) acc[i] = (f32x4){0.f,0.f,0.f,0.f};
    #pragma unroll
    for (int kc=0;kc<8;kc++){
      bf16x8 bfr = *(const bf16x8*)(wpb + (size_t)(wn+col)*256 + kc*32 + quad*8);
      #pragma unroll
      for (int mi=0;mi<4;mi++){
        bf16x8 af = *(const bf16x8*)&sxc[mi*16 + col][kc*32 + quad*8];
        acc[mi] = __builtin_amdgcn_mfma_f32_16x16x32_bf16(af, bfr, acc[mi], 0, 0, 0);
      }
    }
    #pragma unroll
    for (int mi=0;mi<4;mi++)
      #pragma unroll
      for (int r=0;r<4;r++)
        vls[mi*16 + quad*4 + r][wn + col] = acc[mi][r];
  }
  __syncthreads();

  // ---- phase 2: write vbc[t][16] = C only ----
  #pragma unroll
  for (int p=0;p<4;p++){
    int j = p*256 + tid;           // 1024
    int t = j >> 4, i = j & 15;
    vbc[(m0+t)*16 + i] = vls[t][24+i];
  }

  // ---- phase 3: scanA summary + y_local (packed f32x2, 1-deep LDS prefetch);
  //      store packed (dt, ypart = y_local + u*Dv) ----
  {
    const int d = tid;
    const float a0 = -fast_exp(alog[d*DST]) * L2E;
    bool fast = true;
    for (int s=1;s<16;s++){
      float as = -fast_exp(alog[d*DST + s]) * L2E;
      fast = fast && (fabsf(as - (float)(s+1)*a0) <= 1e-3f*fabsf(as));
    }
    float4 w8a = *(const float4*)(dtw + d*8);
    float4 w8b = *(const float4*)(dtw + d*8 + 4);
    const f32x2 wA0 = {w8a.x, w8a.y}, wA1 = {w8a.z, w8a.w};
    const f32x2 wB0 = {w8b.x, w8b.y}, wB1 = {w8b.z, w8b.w};
    const float bd = dtb[d];
    const float Dv = Dpar[d];
    float ssum = 0.f;
    size_t base = (((size_t)b*NSEG + g)*DIN + d)*DST;
    if (fast){
      f32x2 hp[8];
      #pragma unroll
      for (int k=0;k<8;k++) hp[k] = (f32x2){0.f,0.f};
      float4 cv0 = *(const float4*)&vls[0][0];
      float4 cv1 = *(const float4*)&vls[0][4];
      float4 cbb0 = *(const float4*)&vls[0][8];
      float4 cbb1 = *(const float4*)&vls[0][12];
      float4 cbb2 = *(const float4*)&vls[0][16];
      float4 cbb3 = *(const float4*)&vls[0][20];
      float4 ccc0 = *(const float4*)&vls[0][24];
      float4 ccc1 = *(const float4*)&vls[0][28];
      float4 ccc2 = *(const float4*)&vls[0][32];
      float4 ccc3 = *(const float4*)&vls[0][36];
      float cu = (float)sxc[0][d];
      #pragma unroll 2
      for (int t=0;t<SEG;t++){
        float4 v0=cv0, v1=cv1;
        float4 b0=cbb0, b1=cbb1, b2=cbb2, b3=cbb3;
        float4 c0=ccc0, c1=ccc1, c2=ccc2, c3=ccc3;
        float u = cu;
        int tn = (t < SEG-1) ? t+1 : SEG-1;
        cv0 = *(const float4*)&vls[tn][0];
        cv1 = *(const float4*)&vls[tn][4];
        cbb0 = *(const float4*)&vls[tn][8];
        cbb1 = *(const float4*)&vls[tn][12];
        cbb2 = *(const float4*)&vls[tn][16];
        cbb3 = *(const float4*)&vls[tn][20];
        ccc0 = *(const float4*)&vls[tn][24];
        ccc1 = *(const float4*)&vls[tn][28];
        ccc2 = *(const float4*)&vls[tn][32];
        ccc3 = *(const float4*)&vls[tn][36];
        cu = (float)sxc[tn][d];
        f32x2 la = pkfma((f32x2){v0.x,v0.y}, wA0, (f32x2){bd, 0.f});
        la = pkfma((f32x2){v0.z,v0.w}, wA1, la);
        la = pkfma((f32x2){v1.x,v1.y}, wB0, la);
        la = pkfma((f32x2){v1.z,v1.w}, wB1, la);
        float dt = softplusf(la.x + la.y);
        ssum += dt;
        float du = dt*u;
        float r1 = fexp2(dt*a0);
        float r2 = r1*r1, r4 = r2*r2, r8 = r4*r4;
        f32x2 p01 = {r1, r2};
        f32x2 s2 = {r2, r2}, s4 = {r4, r4}, s8 = {r8, r8};
        f32x2 p23 = p01*s2, p45 = p01*s4, p67 = p23*s4;
        f32x2 p89 = p01*s8, pAB = p23*s8, pCD = p45*s8, pEF = p67*s8;
        f32x2 du2 = {du, du};
        f32x2 ya = {0.f,0.f}, yb = {0.f,0.f};
        hp[0] = pkfma(p01, hp[0], du2*(f32x2){b0.x,b0.y});
        ya = pkfma(hp[0], (f32x2){c0.x,c0.y}, ya);
        hp[1] = pkfma(p23, hp[1], du2*(f32x2){b0.z,b0.w});
        yb = pkfma(hp[1], (f32x2){c0.z,c0.w}, yb);
        hp[2] = pkfma(p45, hp[2], du2*(f32x2){b1.x,b1.y});
        ya = pkfma(hp[2], (f32x2){c1.x,c1.y}, ya);
        hp[3] = pkfma(p67, hp[3], du2*(f32x2){b1.z,b1.w});
        yb = pkfma(hp[3], (f32x2){c1.z,c1.w}, yb);
        hp[4] = pkfma(p89, hp[4], du2*(f32x2){b2.x,b2.y});
        ya = pkfma(hp[4], (f32x2){c2.x,c2.y}, ya);
        hp[5] = pkfma(pAB, hp[5], du2*(f32x2){b2.z,b2.w});
        yb = pkfma(hp[5], (f32x2){c2.z,c2.w}, yb);
        hp[6] = pkfma(pCD, hp[6], du2*(f32x2){b3.x,b3.y});
        ya = pkfma(hp[6], (f32x2){c3.x,c3.y}, ya);
        hp[7] = pkfma(pEF, hp[7], du2*(f32x2){b3.z,b3.w});
        yb = pkfma(hp[7], (f32x2){c3.z,c3.w}, yb);
        f32x2 ys = ya + yb;
        float ypart = ys.x + ys.y + u*Dv;
        dub[(m0+t)*DIN + d] = packdu(dt, ypart);
      }
      #pragma unroll
      for (int k=0;k<4;k++){
        float4 o = { hp[2*k].x, hp[2*k].y, hp[2*k+1].x, hp[2*k+1].y };
        *(float4*)(cseg + base + 4*k) = o;
      }
    } else {
      float h[16];
      float aA[16];
      #pragma unroll
      for (int k=0;k<16;k++){ h[k] = 0.f; aA[k] = -fast_exp(alog[d*DST + k]) * L2E; }
      for (int t=0;t<SEG;t++){
        float4 v0 = *(const float4*)&vls[t][0];
        float4 v1 = *(const float4*)&vls[t][4];
        float lin = bd;
        lin = fmaf(v0.x,w8a.x, fmaf(v0.y,w8a.y, fmaf(v0.z,w8a.z, fmaf(v0.w,w8a.w, lin))));
        lin = fmaf(v1.x,w8b.x, fmaf(v1.y,w8b.y, fmaf(v1.z,w8b.z, fmaf(v1.w,w8b.w, lin))));
        float dt = softplusf(lin);
        ssum += dt;
        float u = (float)sxc[t][d];
        float du = dt*u;
        float y = 0.f;
        #pragma unroll
        for (int k=0;k<16;k++){
          float e = fexp2(dt*aA[k]);
          h[k] = fmaf(e, h[k], du*vls[t][8+k]);
          y = fmaf(h[k], vls[t][24+k], y);
        }
        float ypart = y + u*Dv;
        dub[(m0+t)*DIN + d] = packdu(dt, ypart);
      }
      #pragma unroll
      for (int k=0;k<4;k++){
        float4 o = { h[4*k], h[4*k+1], h[4*k+2], h[4*k+3] };
        *(float4*)(cseg + base + 4*k) = o;
      }
    }
    sdtb[((size_t)b*NSEG + g)*DIN + d] = ssum;
  }
}

// ---------------- scanB: serial combine over segments (register-batched) --------------
__global__ __launch_bounds__(256) void k_scanB(float* __restrict__ cseg,
    const float* __restrict__ sdtb, const float* __restrict__ alog){
  int gl = blockIdx.x*256 + threadIdx.x;
  int b   = gl >> 12;
  int rem = gl & 4095;
  int d = rem >> 4, s = rem & 15;
  const float a = -fast_exp(alog[d*DST + s]) * L2E;
  float cvals[NSEG];
  float sdv[NSEG];
  #pragma unroll
  for (int g=0; g<NSEG; g++){
    size_t base = ((size_t)b*NSEG + g)*DIN;
    sdv[g]   = sdtb[base + d];
    cvals[g] = cseg[(base + d)*DST + s];
  }
  float h = 0.f;
  #pragma unroll
  for (int g=0; g<NSEG; g++){
    size_t ci = (((size_t)b*NSEG + g)*DIN + d)*DST + s;
    cseg[ci] = h;
    h = fmaf(fexp2(a*sdv[g]), h, cvals[g]);
  }
}

// ---------------- scanC3: parallel y-correction + gate + out_proj MFMA + residual -----
// y_t = ypart_t + sum_k C_t[k] * h0[k] * q_t^{k+1}, q_t = exp2(a0*cumdt_t).
// No serial state: t-steps are independent (only cumdt is a 1-add chain).
__global__ __launch_bounds__(256) void k_scanC3(float* __restrict__ xres,
    const unsigned int* __restrict__ dub, const float* __restrict__ vbc,
    const __bf16* __restrict__ gzb,
    const float* __restrict__ alog,
    const float* __restrict__ cseg, const __bf16* __restrict__ wout,
    float* __restrict__ rs){
  __shared__ __bf16 sy[64][264];        // gated y (bf16); later aliased as sx fp32
  __shared__ float svbc[64][16];        // C only
  float* sx = (float*)sy;
  const int tid = threadIdx.x;
  const size_t m0 = (size_t)blockIdx.x * 64;
  const int b = (int)(m0 >> 11);
  const int g = (int)((m0 >> 6) & (NSEG-1));

  #pragma unroll
  for (int p=0;p<4;p++){
    int j = p*256 + tid;           // 1024
    int t = j >> 4, i = j & 15;
    svbc[t][i] = vbc[(m0+t)*16 + i];
  }

  // ---- y-correction phase (thread = channel), fully parallel in t ----
  {
    const int d = tid;
    const float a0 = -fast_exp(alog[d*DST]) * L2E;
    bool fast = true;
    for (int s=1;s<16;s++){
      float as = -fast_exp(alog[d*DST + s]) * L2E;
      fast = fast && (fabsf(as - (float)(s+1)*a0) <= 1e-3f*fabsf(as));
    }
    size_t base = (((size_t)b*NSEG + g)*DIN + d)*DST;
    float4 hv0 = *(const float4*)(cseg + base);
    float4 hv1 = *(const float4*)(cseg + base + 4);
    float4 hv2 = *(const float4*)(cseg + base + 8);
    float4 hv3 = *(const float4*)(cseg + base + 12);
    __syncthreads();   // svbc staged

    if (fast){
      const f32x2 e01={hv0.x,hv0.y}, e23={hv0.z,hv0.w}, e45={hv1.x,hv1.y}, e67={hv1.z,hv1.w};
      const f32x2 e89={hv2.x,hv2.y}, eAB={hv2.z,hv2.w}, eCD={hv3.x,hv3.y}, eEF={hv3.z,hv3.w};
      float cum = 0.f;

#define LOADCH(WV,GV,T0) \
      _Pragma("unroll") \
      for (int q=0;q<8;q++){ \
        WV[q] = dub[(m0 + (T0) + q)*DIN + d]; \
        GV[q] = gzb[(m0 + (T0) + q)*DIN + d]; \
      }

#define SCSTEP(T,WW,GG) { \
      float ypart = __builtin_bit_cast(float, (WW) & 0xffff0000u); \
      float dt    = __builtin_bit_cast(float, (WW) << 16); \
      cum += dt; \
      float r1 = fexp2(cum*a0); \
      float r2 = r1*r1, r4 = r2*r2, r8 = r4*r4; \
      f32x2 p01 = {r1, r2}; \
      f32x2 s2 = {r2, r2}, s4 = {r4, r4}, s8 = {r8, r8}; \
      f32x2 p23 = p01*s2, p45 = p01*s4, p67 = p23*s4; \
      f32x2 p89 = p01*s8, pAB = p23*s8, pCD = p45*s8, pEF = p67*s8; \
      float4 c0 = *(const float4*)&svbc[T][0]; \
      float4 c1 = *(const float4*)&svbc[T][4]; \
      float4 c2 = *(const float4*)&svbc[T][8]; \
      float4 c3 = *(const float4*)&svbc[T][12]; \
      f32x2 ya = {0.f,0.f}, yb = {0.f,0.f}; \
      ya = pkfma(p01*e01, (f32x2){c0.x,c0.y}, ya); \
      yb = pkfma(p23*e23, (f32x2){c0.z,c0.w}, yb); \
      ya = pkfma(p45*e45, (f32x2){c1.x,c1.y}, ya); \
      yb = pkfma(p67*e67, (f32x2){c1.z,c1.w}, yb); \
      ya = pkfma(p89*e89, (f32x2){c2.x,c2.y}, ya); \
      yb = pkfma(pAB*eAB, (f32x2){c2.z,c2.w}, yb); \
      ya = pkfma(pCD*eCD, (f32x2){c3.x,c3.y}, ya); \
      yb = pkfma(pEF*eEF, (f32x2){c3.z,c3.w}, yb); \
      f32x2 ys = ya + yb; \
      float y = ypart + ys.x + ys.y; \
      sy[T][d] = (__bf16)(y * (float)(GG)); }

      unsigned int wv0[8], wv1[8];
      __bf16 gv0[8], gv1[8];
      LOADCH(wv0, gv0, 0)
      #pragma unroll
      for (int tc=0; tc<SEG; tc+=16){
        LOADCH(wv1, gv1, tc+8)
        #pragma unroll
        for (int q=0;q<8;q++){ SCSTEP(tc+q, wv0[q], gv0[q]) }
        if (tc+16 < SEG){ LOADCH(wv0, gv0, tc+16) }
        #pragma unroll
        for (int q=0;q<8;q++){ SCSTEP(tc+8+q, wv1[q], gv1[q]) }
      }
#undef LOADCH
#undef SCSTEP
    } else {
      float e[16] = {hv0.x,hv0.y,hv0.z,hv0.w, hv1.x,hv1.y,hv1.z,hv1.w,
                     hv2.x,hv2.y,hv2.z,hv2.w, hv3.x,hv3.y,hv3.z,hv3.w};
      float aA[16];
      #pragma unroll
      for (int k=0;k<16;k++) aA[k] = -fast_exp(alog[d*DST + k]) * L2E;
      float cum = 0.f;
      for (int t=0;t<SEG;t++){
        unsigned int w = dub[(m0+t)*DIN + d];
        float ypart = __builtin_bit_cast(float, w & 0xffff0000u);
        float dt    = __builtin_bit_cast(float, w << 16);
        cum += dt;
        float y = ypart;
        #pragma unroll
        for (int k=0;k<16;k++)
          y = fmaf(e[k]*fexp2(aA[k]*cum), svbc[t][k], y);
        float gz = (float)gzb[(m0+t)*DIN + d];
        sy[t][d] = (__bf16)(y * gz);
      }
    }
  }
  __syncthreads();   // sy complete

  // ---- out_proj MFMA: newx[64][128] = sy[64x256] @ wout[128x256]^T + xres ----
  const int wave = tid >> 6, lane = tid & 63;
  const int col = lane & 15, quad = lane >> 4;
  const int wn = wave * 32;
  f32x4 acc[4][2];
  #pragma unroll
  for (int i=0;i<4;i++)
    #pragma unroll
    for (int j=0;j<2;j++) acc[i][j] = (f32x4){0.f,0.f,0.f,0.f};
  #pragma unroll
  for (int kc=0;kc<8;kc++){
    bf16x8 bfr0 = *(const bf16x8*)(wout + (size_t)(wn +      col)*256 + kc*32 + quad*8);
    bf16x8 bfr1 = *(const bf16x8*)(wout + (size_t)(wn + 16 + col)*256 + kc*32 + quad*8);
    #pragma unroll
    for (int mi=0;mi<4;mi++){
      bf16x8 af = *(const bf16x8*)&sy[mi*16 + col][kc*32 + quad*8];
      acc[mi][0] = __builtin_amdgcn_mfma_f32_16x16x32_bf16(af, bfr0, acc[mi][0], 0, 0, 0);
      acc[mi][1] = __builtin_amdgcn_mfma_f32_16x16x32_bf16(af, bfr1, acc[mi][1], 0, 0, 0);
    }
  }
  __syncthreads();   // sy reads done; sx may now overwrite

  // ---- epilogue: residual add -> global + LDS(sx); then rms for next layer ----
  #pragma unroll
  for (int mi=0;mi<4;mi++){
    #pragma unroll
    for (int j=0;j<2;j++){
      int n = wn + j*16 + col;
      #pragma unroll
      for (int r=0;r<4;r++){
        int ml = mi*16 + quad*4 + r;
        size_t go = (m0 + ml)*DMODEL + n;
        float nx = xres[go] + acc[mi][j][r];
        xres[go] = nx;
        sx[ml*132 + n] = nx;
      }
    }
  }
  __syncthreads();
  {
    int row = tid >> 2, q = tid & 3;
    const float* pr = sx + row*132 + q*32;
    float ss = 0.f;
    #pragma unroll
    for (int i=0;i<32;i+=4){
      float4 v = *(const float4*)(pr + i);
      ss += v.x*v.x + v.y*v.y + v.z*v.z + v.w*v.w;
    }
    ss += __shfl_xor(ss, 1);
    ss += __shfl_xor(ss, 2);
    if (q == 0) rs[m0 + row] = rsqrtf(ss*(1.f/128.f) + 1e-5f);
  }
}

// ---------------- masked mean pool over a chunk ----------------
__global__ __launch_bounds__(256) void k_pool1(const float* __restrict__ x,
    const float* __restrict__ mask, float* __restrict__ part, float* __restrict__ pmask){
  int b = blockIdx.y, seg = blockIdx.x;
  int d = threadIdx.x & 127, half = threadIdx.x >> 7;
  int t0 = seg*128 + half*64;
  float acc = 0.f, macc = 0.f;
  for (int i=0;i<64;i++){
    int t = t0 + i;
    float mv = mask[(size_t)b*SL + t];
    acc = fmaf(x[((size_t)b*SL + t)*DMODEL + d], mv, acc);
    macc += mv;
  }
  __shared__ float sm[256];
  __shared__ float smm[2];
  sm[threadIdx.x] = acc;
  if (d == 0) smm[half] = macc;
  __syncthreads();
  if (half == 0){
    part[((size_t)b*16 + seg)*128 + d] = sm[d] + sm[128+d];
    if (d == 0) pmask[b*16 + seg] = smm[0] + smm[1];
  }
}

// ---------------- fused head: pool2 + mlp1 + mlp2 + mlp3 ----------------
__global__ __launch_bounds__(512) void k_head(const float* __restrict__ part,
    const float* __restrict__ pmask,
    const float* __restrict__ l1w, const float* __restrict__ l1b,
    const float* __restrict__ l2w, const float* __restrict__ l2b,
    const float* __restrict__ l3w, const float* __restrict__ l3b,
    float* __restrict__ out){
  __shared__ float sp[128];
  __shared__ float sh[512];
  int b = blockIdx.x, tid = threadIdx.x;
  if (tid < 128){
    float acc = 0.f, ms = 0.f;
    for (int s=0;s<16;s++){
      acc += part[((size_t)b*16+s)*128 + tid];
      ms  += pmask[b*16+s];
    }
    sp[tid] = acc / fmaxf(ms, 1e-9f);
  }
  __syncthreads();
  {
    const float4* pw = (const float4*)(l1w + (size_t)tid*128);
    const float4* pi = (const float4*)sp;
    float acc = 0.f;
    #pragma unroll 8
    for (int k=0;k<32;k++){
      float4 a = pi[k], w = pw[k];
      acc = fmaf(a.x,w.x, fmaf(a.y,w.y, fmaf(a.z,w.z, fmaf(a.w,w.w, acc))));
    }
    __syncthreads();
    sh[tid] = fmaxf(acc + l1b[tid], 0.f);
  }
  __syncthreads();
  float h2v;
  {
    const float4* pw = (const float4*)(l2w + (size_t)tid*512);
    const float4* pi = (const float4*)sh;
    float acc = 0.f;
    #pragma unroll 8
    for (int k=0;k<128;k++){
      float4 a = pi[k], w = pw[k];
      acc = fmaf(a.x,w.x, fmaf(a.y,w.y, fmaf(a.z,w.z, fmaf(a.w,w.w, acc))));
    }
    h2v = fmaxf(acc + l2b[tid], 0.f);
  }
  __syncthreads();
  sh[tid] = h2v;
  __syncthreads();
  if (tid < 192){
    int n = tid >> 6, lane = tid & 63;
    float acc = 0.f;
    for (int k=lane; k<512; k+=64) acc = fmaf(sh[k], l3w[(size_t)n*512+k], acc);
    #pragma unroll
    for (int m=1;m<64;m<<=1) acc += __shfl_xor(acc, m);
    if (lane == 0) out[(size_t)b*3 + n] = acc + l3b[n];
  }
}

// ---------------- launch ----------------
extern "C" void kernel_launch(void* const* d_in, const int* in_sizes, int n_in,
                              void* d_out, int out_size, void* d_ws, size_t ws_size,
                              hipStream_t stream){
  const int*   tokens = (const int*)  d_in[0];
  const float* mask   = (const float*)d_in[1];
  const float* emb    = (const float*)d_in[2];
  const float* bn_w   = (const float*)d_in[3];
  const float* bn_b   = (const float*)d_in[4];
  const float* conv_w = (const float*)d_in[5];
  const float* conv_b = (const float*)d_in[6];
  const float* in_w   = (const float*)d_in[7];
  const float* c1_w   = (const float*)d_in[8];
  const float* c1_b   = (const float*)d_in[9];
  const float* xp_w   = (const float*)d_in[10];
  const float* dtp_w  = (const float*)d_in[11];
  const float* dtp_b  = (const float*)d_in[12];
  const float* A_log  = (const float*)d_in[13];
  const float* D_par  = (const float*)d_in[14];
  const float* out_w  = (const float*)d_in[15];
  const float* nrm_w  = (const float*)d_in[16];
  const float* l1w = (const float*)d_in[17]; const float* l1b = (const float*)d_in[18];
  const float* l2w = (const float*)d_in[19]; const float* l2b = (const float*)d_in[20];
  const float* l3w = (const float*)d_in[21]; const float* l3b = (const float*)d_in[22];
  float* dout = (float*)d_out;

  // per-token floats: x 128 + rs 1 + xi(bf16) 128 + dub(uint) 256 + vbc 16 + cseg 64
  //                   + sdt 4 + gz(bf16) 128 = 725
  int CB = 64;
  while (CB > 1 && ((size_t)CB*SL*725 + FIX_END)*4 > ws_size) CB >>= 1;
  if (((size_t)CB*SL*725 + FIX_END)*4 > ws_size) return;
  const size_t CTOK = (size_t)CB*SL;

  float* ws  = (float*)d_ws;
  float* pl  = ws + FIX_PL;
  float* pm  = ws + FIX_PM;
  __bf16* wpb   = (__bf16*)(ws + FIX_WP);
  __bf16* w2b   = (__bf16*)(ws + FIX_W2B);
  __bf16* winb  = (__bf16*)(ws + FIX_WINB);
  __bf16* woutb = (__bf16*)(ws + FIX_WOUTB);
  float* xcb = ws + FIX_END;                 // CTOK*128 fp32 residual x
  float* rs  = xcb + CTOK*128;               // CTOK
  __bf16* xib = (__bf16*)(rs + CTOK);        // CTOK*256 bf16 (x-branch)
  unsigned int* dub = (unsigned int*)(xib + CTOK*256);   // CTOK*256 uint (packed dt,ypart)
  float* vbc = (float*)(dub + CTOK*256);     // CTOK*16 fp32 (C only)
  float* csg = vbc + CTOK*16;                // CTOK*64
  float* sdt = csg + CTOK*64;                // CTOK*4
  __bf16* zb  = (__bf16*)(sdt + CTOK*4);     // CTOK*256 bf16 (gz)

  k_w2b<<<192, 256, 0, stream>>>(conv_w, w2b);
  k_cvt<<<1024, 256, 0, stream>>>(in_w,  winb,  4*512*128);
  k_cvt<<<512,  256, 0, stream>>>(out_w, woutb, 4*128*256);
  k_wprep<<<256, 256, 0, stream>>>(xp_w, wpb);

  const int nchunks = NB / CB;
  for (int c = 0; c < nchunks; c++){
    const int* tok_c = tokens + (size_t)c*CTOK;

    k_mgemm<0,384,128><<<dim3(1, CTOK/128), 256, 0, stream>>>(
        tok_c, w2b, conv_b, emb, bn_w, bn_b, xcb, nullptr, nullptr);
    k_rmsscale<<<CTOK/4, 256, 0, stream>>>(xcb, rs);

    for (int layer = 0; layer < NLAYER; layer++){
      const __bf16* lin = winb  + (size_t)layer*512*128;
      const float* lcw  = c1_w  + (size_t)layer*DIN*4;
      const float* lcb  = c1_b  + (size_t)layer*DIN;
      const float* ldw  = dtp_w + (size_t)layer*DIN*8;
      const float* ldb  = dtp_b + (size_t)layer*DIN;
      const float* lal  = A_log + (size_t)layer*DIN*DST;
      const float* lD   = D_par + (size_t)layer*DIN;
      const __bf16* low = woutb + (size_t)layer*128*256;
      const float* lnw  = nrm_w + (size_t)layer*128;

      k_mgemm<1,128,512><<<dim3(4, CTOK/128), 256, 0, stream>>>(
          xcb, lin, nullptr, rs, lnw, nullptr, nullptr, xib, zb);
      k_seg<<<(int)(CTOK/64), 256, 0, stream>>>(
          xib, wpb + (size_t)layer*64*256, lcw, lcb, ldw, ldb, lal, lD, vbc, dub, csg, sdt);
      k_scanB<<<CB*16, 256, 0, stream>>>(csg, sdt, lal);
      k_scanC3<<<(int)(CTOK/64), 256, 0, stream>>>(
          xcb, dub, vbc, zb, lal, csg, low, rs);
    }

    k_pool1<<<dim3(16, CB), 256, 0, stream>>>(
        xcb, mask + (size_t)c*CTOK, pl + (size_t)c*CB*16*128, pm + (size_t)c*CB*16);
  }

  k_head<<<NB, 512, 0, stream>>>(pl, pm, l1w, l1b, l2w, l2b, l3w, l3b, dout);
}

// Round 6
// 1306.694 us; speedup vs baseline: 1.1015x; 1.1015x over previous
//
#include <hip/hip_runtime.h>
#include <math.h>

// ---------------- problem constants ----------------
#define NB     64
#define SL     2048
#define NTOK   (NB*SL)
#define EMB_D  128
#define DMODEL 128
#define DIN    256
#define DST    16
#define NLAYER 4
#define SEG    64
#define NSEG   (SL/SEG)        // 32
#define L2E    1.4426950408889634f
#define LN2    0.6931471805599453f

typedef __bf16 bf16x8 __attribute__((ext_vector_type(8)));
typedef __bf16 bf16x4 __attribute__((ext_vector_type(4)));
typedef float  f32x4  __attribute__((ext_vector_type(4)));
typedef float  f32x2  __attribute__((ext_vector_type(2)));

// fixed small region (floats)
#define FIX_PL   ((size_t)0)
#define FIX_PM   (FIX_PL + 262144)
#define FIX_WP   (FIX_PM + 2048)
#define FIX_W2B  (FIX_WP + 65536)
#define FIX_WINB (FIX_W2B + 24576)
#define FIX_WOUTB (FIX_WINB + 131072)
#define FIX_END  (FIX_WOUTB + 65536)

// raw-instruction transcendentals
__device__ __forceinline__ float fexp2(float x){ return __builtin_amdgcn_exp2f(x); }
__device__ __forceinline__ float flog2(float x){ return __builtin_amdgcn_logf(x); }
__device__ __forceinline__ float frcp (float x){ return __builtin_amdgcn_rcpf(x); }
__device__ __forceinline__ float fast_exp(float x){ return fexp2(x*L2E); }
__device__ __forceinline__ float siluf(float v){ return v * frcp(1.f + fast_exp(-v)); }
__device__ __forceinline__ float softplusf(float a){
  return fmaxf(a,0.f) + flog2(1.f + fexp2(-fabsf(a)*L2E)) * LN2;
}
__device__ __forceinline__ unsigned short bfbits(float x){
  __bf16 b = (__bf16)x; return __builtin_bit_cast(unsigned short, b);
}
__device__ __forceinline__ unsigned int packdu(float dt, float u){
  return ((unsigned int)bfbits(u) << 16) | (unsigned int)bfbits(dt);
}

// packed f32 helpers (target: v_pk_fma_f32 / v_pk_mul_f32)
__device__ __forceinline__ f32x2 pkfma(f32x2 a, f32x2 b, f32x2 c){
#if __has_builtin(__builtin_elementwise_fma)
  return __builtin_elementwise_fma(a, b, c);
#else
  return (f32x2){ fmaf(a.x,b.x,c.x), fmaf(a.y,b.y,c.y) };
#endif
}

// ---------------- merged weight prep (was 4 kernels) ----------------
__global__ void k_prep(const float* __restrict__ cw, __bf16* __restrict__ w2,
                       const float* __restrict__ inw, __bf16* __restrict__ winb,
                       const float* __restrict__ outw, __bf16* __restrict__ woutb,
                       const float* __restrict__ xpw, __bf16* __restrict__ wp){
  int g = blockIdx.x*256 + threadIdx.x;
  if (g < 49152){
    int d = g / 384, j = g % 384;
    int k = j >> 7, e = j & 127;
    w2[d*384 + k*128 + e] = (__bf16)cw[d*384 + e*3 + k];
    return;
  }
  int g1 = g - 49152;
  if (g1 < 262144){ winb[g1] = (__bf16)inw[g1]; return; }
  int g2 = g1 - 262144;
  if (g2 < 131072){ woutb[g2] = (__bf16)outw[g2]; return; }
  int g3 = g2 - 131072;
  if (g3 < 65536){
    int l = g3 >> 14, rem = g3 & 16383;
    int n = rem >> 8, k = rem & 255;
    float v = 0.f;
    if (n < 8){
      v = xpw[(size_t)l*40*256 + n*256 + k];
    } else if (n < 40){
      int i = n - 8;
      int row = 8 + ((i&1)<<4) + (i>>1);
      v = xpw[(size_t)l*40*256 + row*256 + k];
    }
    wp[g3] = (__bf16)v;
  }
}

// ---------------- bf16 MFMA GEMM ----------------
// MODE 0: A = inline embed+BN gather from tokens (Av=int* tokens, rsp=emb,
//         nwp=bn_w, bnbp=bn_b), epi relu(+conv bias) -> out fp32, + fused rms -> rso
// MODE 1: A fp32 (x), staged *rs*nw; epi n<256 -> outb (xi bf16), else outz (gz bf16)
template<int MODE, int K, int N>
__global__ __launch_bounds__(256) void k_mgemm(
    const void* __restrict__ Av, const __bf16* __restrict__ Wb,
    const float* __restrict__ bias, const float* __restrict__ rsp,
    const float* __restrict__ nwp, const float* __restrict__ bnbp,
    float* __restrict__ out, __bf16* __restrict__ outb, __bf16* __restrict__ outz,
    float* __restrict__ rso){
  __shared__ __bf16 As[128][40];
  __shared__ __bf16 Bs[128][40];
  const int tid  = threadIdx.x;
  const int wave = tid >> 6;
  const int lane = tid & 63;
  const int col  = lane & 15;
  const int quad = lane >> 4;
  const int wm = (wave & 1) * 64;
  const int wn = (wave >> 1) * 64;
  const int m0 = blockIdx.y * 128;
  const int n0 = blockIdx.x * 128;

  f32x4 acc[4][4];
  #pragma unroll
  for (int i=0;i<4;i++)
    #pragma unroll
    for (int j=0;j<4;j++) acc[i][j] = (f32x4){0.f,0.f,0.f,0.f};

  const int sm = tid >> 3;
  const int sk4 = (tid & 7) * 4;
  const int bn = tid >> 2;
  const int bk8 = (tid & 3) * 8;

  for (int k0 = 0; k0 < K; k0 += 32){
    if constexpr(MODE==0){
      const int* tok = (const int*)Av;
      const int tap = k0 >> 7;
      const int e = (k0 & 127) + sk4;
      const float sc = rsqrtf(1.0f + 1e-5f);
      float4 bw4 = *(const float4*)(nwp + e);
      float4 bb4 = *(const float4*)(bnbp + e);
      float4 s4;
      s4.x = bw4.x*sc; s4.y = bw4.y*sc; s4.z = bw4.z*sc; s4.w = bw4.w*sc;
      #pragma unroll
      for (int p=0;p<4;p++){
        int m = p*32 + sm;
        int tokpos = m0 + m;
        int t = (tokpos & 2047) + tap - 1;
        float4 v = {0.f,0.f,0.f,0.f};
        if ((unsigned)t < 2048u){
          int id = tok[((size_t)(tokpos >> 11) << 11) + t];
          float4 ev = *(const float4*)(rsp + (size_t)id*EMB_D + e);
          v.x = fmaf(ev.x, s4.x, bb4.x);
          v.y = fmaf(ev.y, s4.y, bb4.y);
          v.z = fmaf(ev.z, s4.z, bb4.z);
          v.w = fmaf(ev.w, s4.w, bb4.w);
        }
        bf16x4 o;
        o[0] = (__bf16)v.x; o[1] = (__bf16)v.y; o[2] = (__bf16)v.z; o[3] = (__bf16)v.w;
        *(bf16x4*)&As[m][sk4] = o;
      }
    } else {
      const size_t abase = (size_t)m0 * K;
      #pragma unroll
      for (int p=0;p<4;p++){
        int m = p*32 + sm;
        const float* A = (const float*)Av;
        float4 x4 = *(const float4*)(A + abase + (size_t)m*K + k0 + sk4);
        float4 w4 = *(const float4*)(nwp + k0 + sk4);
        float s = rsp[m0 + m];
        float4 v;
        v.x = x4.x*s*w4.x; v.y = x4.y*s*w4.y; v.z = x4.z*s*w4.z; v.w = x4.w*s*w4.w;
        bf16x4 o;
        o[0] = (__bf16)v.x; o[1] = (__bf16)v.y; o[2] = (__bf16)v.z; o[3] = (__bf16)v.w;
        *(bf16x4*)&As[m][sk4] = o;
      }
    }
    #pragma unroll
    for (int p=0;p<2;p++){
      int n = p*64 + bn;
      bf16x8 w = *(const bf16x8*)(Wb + (size_t)(n0+n)*K + k0 + bk8);
      *(bf16x8*)&Bs[n][bk8] = w;
    }
    __syncthreads();
    bf16x8 af[4], bfr[4];
    const int fq = quad*8;
    #pragma unroll
    for (int i=0;i<4;i++) af[i]  = *(const bf16x8*)&As[wm + i*16 + col][fq];
    #pragma unroll
    for (int j=0;j<4;j++) bfr[j] = *(const bf16x8*)&Bs[wn + j*16 + col][fq];
    #pragma unroll
    for (int i=0;i<4;i++)
      #pragma unroll
      for (int j=0;j<4;j++)
        acc[i][j] = __builtin_amdgcn_mfma_f32_16x16x32_bf16(af[i], bfr[j], acc[i][j], 0, 0, 0);
    __syncthreads();
  }

  if constexpr(MODE==0){
    // epilogue + fused rms (rso): row-sum of squares via shfl + LDS
    float sq[4][4];
    #pragma unroll
    for (int i=0;i<4;i++)
      #pragma unroll
      for (int r=0;r<4;r++) sq[i][r] = 0.f;
    #pragma unroll
    for (int i=0;i<4;i++){
      #pragma unroll
      for (int j=0;j<4;j++){
        int n = n0 + wn + j*16 + col;
        #pragma unroll
        for (int r=0;r<4;r++){
          int m = m0 + wm + i*16 + quad*4 + r;
          float v = fmaxf(acc[i][j][r] + bias[n], 0.f);
          out[(size_t)m*DMODEL + n] = v;
          sq[i][r] = fmaf(v, v, sq[i][r]);
        }
      }
    }
    float* ssq = (float*)As;   // 2*128 floats, As dead after final sync
    #pragma unroll
    for (int i=0;i<4;i++){
      #pragma unroll
      for (int r=0;r<4;r++){
        float s = sq[i][r];
        s += __shfl_xor(s, 1); s += __shfl_xor(s, 2);
        s += __shfl_xor(s, 4); s += __shfl_xor(s, 8);
        if (col == 0) ssq[(wn>>6)*128 + wm + i*16 + quad*4 + r] = s;
      }
    }
    __syncthreads();
    if (tid < 128) rso[m0 + tid] = rsqrtf((ssq[tid] + ssq[128+tid])*(1.f/128.f) + 1e-5f);
  } else {
    #pragma unroll
    for (int i=0;i<4;i++){
      #pragma unroll
      for (int j=0;j<4;j++){
        int n_l = wn + j*16 + col;
        #pragma unroll
        for (int r=0;r<4;r++){
          int m = m0 + wm + i*16 + quad*4 + r;
          float c = acc[i][j][r];
          int n = n0 + n_l;
          if (n < DIN) outb[(size_t)m*DIN + n]        = (__bf16)c;
          else         outz[(size_t)m*DIN + n - DIN]  = (__bf16)siluf(c);
        }
      }
    }
  }
}

// ---------------- fused segment front: dwconv+silu -> MFMA x_proj -> vbc/dub -> scanA ----
__global__ __launch_bounds__(256) void k_seg(const __bf16* __restrict__ xi,
    const __bf16* __restrict__ wpb,
    const float* __restrict__ cw, const float* __restrict__ cb,
    const float* __restrict__ dtw, const float* __restrict__ dtb,
    const float* __restrict__ alog,
    float* __restrict__ vbc, unsigned int* __restrict__ dub,
    float* __restrict__ cseg, float* __restrict__ sdtb){
  __shared__ __bf16 sxc[64][264];
  __shared__ float vls[64][68];
  const int tid = threadIdx.x;
  const size_t m0 = (size_t)blockIdx.x * 64;
  const int b = (int)(m0 >> 11);
  const int g = (int)((m0 >> 6) & (NSEG-1));
  const int seq0 = (int)(m0 & 2047);

  // ---- phase 0: depthwise conv(k=4, bf16 in) + silu, rolling window ----
  {
    const int c4 = (tid & 63) * 4;
    const int tw = tid >> 6;           // 0..3
    const int t0 = tw * 16;
    float wc[4][4];
    #pragma unroll
    for (int j=0;j<4;j++)
      #pragma unroll
      for (int k=0;k<4;k++) wc[j][k] = cw[(c4+j)*4 + k];
    float4 cb4 = *(const float4*)(cb + c4);
    bf16x4 zed;
    zed[0] = (__bf16)0.f; zed[1] = (__bf16)0.f; zed[2] = (__bf16)0.f; zed[3] = (__bf16)0.f;
    bf16x4 win[3];
    #pragma unroll
    for (int j=0;j<3;j++){
      int tr = t0 - 3 + j;
      win[j] = (seq0 + tr >= 0) ? *(const bf16x4*)(xi + (m0 + tr)*DIN + c4) : zed;
    }
    #pragma unroll
    for (int i=0;i<16;i++){
      int t = t0 + i;
      bf16x4 w3 = *(const bf16x4*)(xi + (m0 + t)*DIN + c4);
      float4 acc = cb4;
      #pragma unroll
      for (int k=0;k<3;k++){
        acc.x = fmaf(wc[0][k], (float)win[k][0], acc.x);
        acc.y = fmaf(wc[1][k], (float)win[k][1], acc.y);
        acc.z = fmaf(wc[2][k], (float)win[k][2], acc.z);
        acc.w = fmaf(wc[3][k], (float)win[k][3], acc.w);
      }
      acc.x = fmaf(wc[0][3], (float)w3[0], acc.x);
      acc.y = fmaf(wc[1][3], (float)w3[1], acc.y);
      acc.z = fmaf(wc[2][3], (float)w3[2], acc.z);
      acc.w = fmaf(wc[3][3], (float)w3[3], acc.w);
      bf16x4 o;
      o[0]=(__bf16)siluf(acc.x); o[1]=(__bf16)siluf(acc.y);
      o[2]=(__bf16)siluf(acc.z); o[3]=(__bf16)siluf(acc.w);
      *(bf16x4*)&sxc[t][c4] = o;
      win[0] = win[1]; win[1] = win[2]; win[2] = w3;
    }
  }
  __syncthreads();

  // ---- phase 1: MFMA vls[64][64] = sxc[64x256] @ wpb[64x256]^T ----
  {
    const int wave = tid >> 6, lane = tid & 63;
    const int col = lane & 15, quad = lane >> 4;
    const int wn = wave * 16;
    f32x4 acc[4];
    #pragma unroll
    for (int i=0;i<4;i++) acc[i] = (f32x4){0.f,0.f,0.f,0.f};
    #pragma unroll
    for (int kc=0;kc<8;kc++){
      bf16x8 bfr = *(const bf16x8*)(wpb + (size_t)(wn+col)*256 + kc*32 + quad*8);
      #pragma unroll
      for (int mi=0;mi<4;mi++){
        bf16x8 af = *(const bf16x8*)&sxc[mi*16 + col][kc*32 + quad*8];
        acc[mi] = __builtin_amdgcn_mfma_f32_16x16x32_bf16(af, bfr, acc[mi], 0, 0, 0);
      }
    }
    #pragma unroll
    for (int mi=0;mi<4;mi++)
      #pragma unroll
      for (int r=0;r<4;r++)
        vls[mi*16 + quad*4 + r][wn + col] = acc[mi][r];
  }
  __syncthreads();

  // ---- phase 2: write vbc[t][32] = [B0..B15, C0..C15] ----
  #pragma unroll
  for (int p=0;p<8;p++){
    int j = p*256 + tid;           // 2048
    int t = j >> 5, i = j & 31;
    vbc[(m0+t)*32 + i] = vls[t][8+i];
  }

  // ---- phase 3: scanA summary (packed f32x2, 1-deep LDS prefetch) ----
  {
    const int d = tid;
    const float a0 = -fast_exp(alog[d*DST]) * L2E;
    bool fast = true;
    for (int s=1;s<16;s++){
      float as = -fast_exp(alog[d*DST + s]) * L2E;
      fast = fast && (fabsf(as - (float)(s+1)*a0) <= 1e-3f*fabsf(as));
    }
    float4 w8a = *(const float4*)(dtw + d*8);
    float4 w8b = *(const float4*)(dtw + d*8 + 4);
    const f32x2 wA0 = {w8a.x, w8a.y}, wA1 = {w8a.z, w8a.w};
    const f32x2 wB0 = {w8b.x, w8b.y}, wB1 = {w8b.z, w8b.w};
    const float bd = dtb[d];
    float ssum = 0.f;
    size_t base = (((size_t)b*NSEG + g)*DIN + d)*DST;
    if (fast){
      f32x2 hp[8];
      #pragma unroll
      for (int k=0;k<8;k++) hp[k] = (f32x2){0.f,0.f};
      float4 cv0 = *(const float4*)&vls[0][0];
      float4 cv1 = *(const float4*)&vls[0][4];
      float4 cb0 = *(const float4*)&vls[0][8];
      float4 cb1 = *(const float4*)&vls[0][12];
      float4 cb2 = *(const float4*)&vls[0][16];
      float4 cb3 = *(const float4*)&vls[0][20];
      float cu = (float)sxc[0][d];
      #pragma unroll 2
      for (int t=0;t<SEG;t++){
        float4 v0=cv0, v1=cv1, b0=cb0, b1=cb1, b2=cb2, b3=cb3;
        float u = cu;
        int tn = (t < SEG-1) ? t+1 : SEG-1;
        cv0 = *(const float4*)&vls[tn][0];
        cv1 = *(const float4*)&vls[tn][4];
        cb0 = *(const float4*)&vls[tn][8];
        cb1 = *(const float4*)&vls[tn][12];
        cb2 = *(const float4*)&vls[tn][16];
        cb3 = *(const float4*)&vls[tn][20];
        cu = (float)sxc[tn][d];
        f32x2 la = pkfma((f32x2){v0.x,v0.y}, wA0, (f32x2){bd, 0.f});
        la = pkfma((f32x2){v0.z,v0.w}, wA1, la);
        la = pkfma((f32x2){v1.x,v1.y}, wB0, la);
        la = pkfma((f32x2){v1.z,v1.w}, wB1, la);
        float dt = softplusf(la.x + la.y);
        ssum += dt;
        dub[(m0+t)*DIN + d] = packdu(dt, u);
        float du = dt*u;
        float r1 = fexp2(dt*a0);
        float r2 = r1*r1, r4 = r2*r2, r8 = r4*r4;
        f32x2 p01 = {r1, r2};
        f32x2 s2 = {r2, r2}, s4 = {r4, r4}, s8 = {r8, r8};
        f32x2 p23 = p01*s2, p45 = p01*s4, p67 = p23*s4;
        f32x2 p89 = p01*s8, pAB = p23*s8, pCD = p45*s8, pEF = p67*s8;
        f32x2 du2 = {du, du};
        hp[0] = pkfma(p01, hp[0], du2*(f32x2){b0.x,b0.y});
        hp[1] = pkfma(p23, hp[1], du2*(f32x2){b0.z,b0.w});
        hp[2] = pkfma(p45, hp[2], du2*(f32x2){b1.x,b1.y});
        hp[3] = pkfma(p67, hp[3], du2*(f32x2){b1.z,b1.w});
        hp[4] = pkfma(p89, hp[4], du2*(f32x2){b2.x,b2.y});
        hp[5] = pkfma(pAB, hp[5], du2*(f32x2){b2.z,b2.w});
        hp[6] = pkfma(pCD, hp[6], du2*(f32x2){b3.x,b3.y});
        hp[7] = pkfma(pEF, hp[7], du2*(f32x2){b3.z,b3.w});
      }
      #pragma unroll
      for (int k=0;k<4;k++){
        float4 o = { hp[2*k].x, hp[2*k].y, hp[2*k+1].x, hp[2*k+1].y };
        *(float4*)(cseg + base + 4*k) = o;
      }
    } else {
      float h[16];
      float aA[16];
      #pragma unroll
      for (int k=0;k<16;k++){ h[k] = 0.f; aA[k] = -fast_exp(alog[d*DST + k]) * L2E; }
      for (int t=0;t<SEG;t++){
        float4 v0 = *(const float4*)&vls[t][0];
        float4 v1 = *(const float4*)&vls[t][4];
        float lin = bd;
        lin = fmaf(v0.x,w8a.x, fmaf(v0.y,w8a.y, fmaf(v0.z,w8a.z, fmaf(v0.w,w8a.w, lin))));
        lin = fmaf(v1.x,w8b.x, fmaf(v1.y,w8b.y, fmaf(v1.z,w8b.z, fmaf(v1.w,w8b.w, lin))));
        float dt = softplusf(lin);
        ssum += dt;
        float u = (float)sxc[t][d];
        dub[(m0+t)*DIN + d] = packdu(dt, u);
        float du = dt*u;
        #pragma unroll
        for (int k=0;k<16;k++){
          float e = fexp2(dt*aA[k]);
          h[k] = fmaf(e, h[k], du*vls[t][8+k]);
        }
      }
      #pragma unroll
      for (int k=0;k<4;k++){
        float4 o = { h[4*k], h[4*k+1], h[4*k+2], h[4*k+3] };
        *(float4*)(cseg + base + 4*k) = o;
      }
    }
    sdtb[((size_t)b*NSEG + g)*DIN + d] = ssum;
  }
}

// ---------------- scanB: serial combine over segments (register-batched) --------------
__global__ __launch_bounds__(256) void k_scanB(float* __restrict__ cseg,
    const float* __restrict__ sdtb, const float* __restrict__ alog){
  int gl = blockIdx.x*256 + threadIdx.x;
  int b   = gl >> 12;
  int rem = gl & 4095;
  int d = rem >> 4, s = rem & 15;
  const float a = -fast_exp(alog[d*DST + s]) * L2E;
  float cvals[NSEG];
  float sdv[NSEG];
  #pragma unroll
  for (int g=0; g<NSEG; g++){
    size_t base = ((size_t)b*NSEG + g)*DIN;
    sdv[g]   = sdtb[base + d];
    cvals[g] = cseg[(base + d)*DST + s];
  }
  float h = 0.f;
  #pragma unroll
  for (int g=0; g<NSEG; g++){
    size_t ci = (((size_t)b*NSEG + g)*DIN + d)*DST + s;
    cseg[ci] = h;
    h = fmaf(fexp2(a*sdv[g]), h, cvals[g]);
  }
}

// ---------------- scanC3: scan + gate + out_proj MFMA + residual + rms / pool --------
// LAST=0: epilogue computes next-layer rms into rs, writes xres.
// LAST=1: epilogue computes masked pool partials (part/pmask), skips xres write & rms.
template<int LAST>
__global__ __launch_bounds__(256) void k_scanC3(float* __restrict__ xres,
    const unsigned int* __restrict__ dub, const float* __restrict__ vbc,
    const __bf16* __restrict__ gzb,
    const float* __restrict__ alog, const float* __restrict__ Dpar,
    const float* __restrict__ cseg, const __bf16* __restrict__ wout,
    float* __restrict__ rs,
    const float* __restrict__ mask, float* __restrict__ part,
    float* __restrict__ pmask){
  __shared__ __bf16 sy[64][264];        // gated y (bf16); later aliased as sx fp32
  __shared__ float svbc[64][32];        // [B0..B15, C0..C15]; reused as pool scratch
  float* sx = (float*)sy;
  const int tid = threadIdx.x;
  const size_t m0 = (size_t)blockIdx.x * 64;
  const int b = (int)(m0 >> 11);
  const int g = (int)((m0 >> 6) & (NSEG-1));

  #pragma unroll
  for (int p=0;p<8;p++){
    int j = p*256 + tid;           // 2048
    int t = j >> 5, i = j & 31;
    svbc[t][i] = vbc[(m0+t)*32 + i];
  }

  // ---- scan phase: packed f32x2, 8-deep global prefetch + 1-deep LDS ping-pong ----
  {
    const int d = tid;
    const float a0 = -fast_exp(alog[d*DST]) * L2E;
    bool fast = true;
    for (int s=1;s<16;s++){
      float as = -fast_exp(alog[d*DST + s]) * L2E;
      fast = fast && (fabsf(as - (float)(s+1)*a0) <= 1e-3f*fabsf(as));
    }
    const float Dv = Dpar[d];
    size_t base = (((size_t)b*NSEG + g)*DIN + d)*DST;
    float4 hv0 = *(const float4*)(cseg + base);
    float4 hv1 = *(const float4*)(cseg + base + 4);
    float4 hv2 = *(const float4*)(cseg + base + 8);
    float4 hv3 = *(const float4*)(cseg + base + 12);
    __syncthreads();   // svbc staged

    if (fast){
      f32x2 hp[8] = { {hv0.x,hv0.y},{hv0.z,hv0.w},{hv1.x,hv1.y},{hv1.z,hv1.w},
                      {hv2.x,hv2.y},{hv2.z,hv2.w},{hv3.x,hv3.y},{hv3.z,hv3.w} };

#define LOADCH(WV,GV,T0) \
      _Pragma("unroll") \
      for (int q=0;q<8;q++){ \
        WV[q] = dub[(m0 + (T0) + q)*DIN + d]; \
        GV[q] = gzb[(m0 + (T0) + q)*DIN + d]; \
      }

#define SCSTEP(T,WW,GG) { \
      int Tn = ((T) < SEG-1) ? (T)+1 : SEG-1; \
      float4 nb0 = *(const float4*)&svbc[Tn][0]; \
      float4 nb1 = *(const float4*)&svbc[Tn][4]; \
      float4 nb2 = *(const float4*)&svbc[Tn][8]; \
      float4 nb3 = *(const float4*)&svbc[Tn][12]; \
      float4 nb4 = *(const float4*)&svbc[Tn][16]; \
      float4 nb5 = *(const float4*)&svbc[Tn][20]; \
      float4 nb6 = *(const float4*)&svbc[Tn][24]; \
      float4 nb7 = *(const float4*)&svbc[Tn][28]; \
      float u  = __builtin_bit_cast(float, (WW) & 0xffff0000u); \
      float dt = __builtin_bit_cast(float, (WW) << 16); \
      float du = dt*u; \
      float r1 = fexp2(dt*a0); \
      float r2 = r1*r1, r4 = r2*r2, r8 = r4*r4; \
      f32x2 p01 = {r1, r2}; \
      f32x2 s2 = {r2, r2}, s4 = {r4, r4}, s8 = {r8, r8}; \
      f32x2 p23 = p01*s2, p45 = p01*s4, p67 = p23*s4; \
      f32x2 p89 = p01*s8, pAB = p23*s8, pCD = p45*s8, pEF = p67*s8; \
      f32x2 du2 = {du, du}; \
      f32x2 ya = {0.f,0.f}, yb = {0.f,0.f}; \
      hp[0] = pkfma(p01, hp[0], du2*(f32x2){pb0.x,pb0.y}); \
      ya = pkfma(hp[0], (f32x2){pb4.x,pb4.y}, ya); \
      hp[1] = pkfma(p23, hp[1], du2*(f32x2){pb0.z,pb0.w}); \
      yb = pkfma(hp[1], (f32x2){pb4.z,pb4.w}, yb); \
      hp[2] = pkfma(p45, hp[2], du2*(f32x2){pb1.x,pb1.y}); \
      ya = pkfma(hp[2], (f32x2){pb5.x,pb5.y}, ya); \
      hp[3] = pkfma(p67, hp[3], du2*(f32x2){pb1.z,pb1.w}); \
      yb = pkfma(hp[3], (f32x2){pb5.z,pb5.w}, yb); \
      hp[4] = pkfma(p89, hp[4], du2*(f32x2){pb2.x,pb2.y}); \
      ya = pkfma(hp[4], (f32x2){pb6.x,pb6.y}, ya); \
      hp[5] = pkfma(pAB, hp[5], du2*(f32x2){pb2.z,pb2.w}); \
      yb = pkfma(hp[5], (f32x2){pb6.z,pb6.w}, yb); \
      hp[6] = pkfma(pCD, hp[6], du2*(f32x2){pb3.x,pb3.y}); \
      ya = pkfma(hp[6], (f32x2){pb7.x,pb7.y}, ya); \
      hp[7] = pkfma(pEF, hp[7], du2*(f32x2){pb3.z,pb3.w}); \
      yb = pkfma(hp[7], (f32x2){pb7.z,pb7.w}, yb); \
      f32x2 ys = ya + yb; \
      float y = ys.x + ys.y; \
      sy[T][d] = (__bf16)((y + u*Dv) * (float)(GG)); \
      pb0=nb0; pb1=nb1; pb2=nb2; pb3=nb3; pb4=nb4; pb5=nb5; pb6=nb6; pb7=nb7; }

      unsigned int wv0[8], wv1[8];
      __bf16 gv0[8], gv1[8];
      LOADCH(wv0, gv0, 0)
      float4 pb0 = *(const float4*)&svbc[0][0];
      float4 pb1 = *(const float4*)&svbc[0][4];
      float4 pb2 = *(const float4*)&svbc[0][8];
      float4 pb3 = *(const float4*)&svbc[0][12];
      float4 pb4 = *(const float4*)&svbc[0][16];
      float4 pb5 = *(const float4*)&svbc[0][20];
      float4 pb6 = *(const float4*)&svbc[0][24];
      float4 pb7 = *(const float4*)&svbc[0][28];
      #pragma unroll
      for (int tc=0; tc<SEG; tc+=16){
        LOADCH(wv1, gv1, tc+8)
        #pragma unroll
        for (int q=0;q<8;q++){ SCSTEP(tc+q, wv0[q], gv0[q]) }
        if (tc+16 < SEG){ LOADCH(wv0, gv0, tc+16) }
        #pragma unroll
        for (int q=0;q<8;q++){ SCSTEP(tc+8+q, wv1[q], gv1[q]) }
      }
#undef LOADCH
#undef SCSTEP
    } else {
      float h[16] = {hv0.x,hv0.y,hv0.z,hv0.w, hv1.x,hv1.y,hv1.z,hv1.w,
                     hv2.x,hv2.y,hv2.z,hv2.w, hv3.x,hv3.y,hv3.z,hv3.w};
      float aA[16];
      #pragma unroll
      for (int k=0;k<16;k++) aA[k] = -fast_exp(alog[d*DST + k]) * L2E;
      for (int t=0;t<SEG;t++){
        unsigned int w = dub[(m0+t)*DIN + d];
        float u  = __builtin_bit_cast(float, w & 0xffff0000u);
        float dt = __builtin_bit_cast(float, w << 16);
        float du = dt*u;
        float y = 0.f;
        #pragma unroll
        for (int k=0;k<16;k++){
          float e = fexp2(dt*aA[k]);
          h[k] = fmaf(e, h[k], du*svbc[t][k]);
          y = fmaf(h[k], svbc[t][16+k], y);
        }
        float gz = (float)gzb[(m0+t)*DIN + d];
        sy[t][d] = (__bf16)((y + u*Dv) * gz);
      }
    }
  }
  __syncthreads();   // sy complete

  // ---- out_proj MFMA: newx[64][128] = sy[64x256] @ wout[128x256]^T + xres ----
  const int wave = tid >> 6, lane = tid & 63;
  const int col = lane & 15, quad = lane >> 4;
  const int wn = wave * 32;
  f32x4 acc[4][2];
  #pragma unroll
  for (int i=0;i<4;i++)
    #pragma unroll
    for (int j=0;j<2;j++) acc[i][j] = (f32x4){0.f,0.f,0.f,0.f};
  #pragma unroll
  for (int kc=0;kc<8;kc++){
    bf16x8 bfr0 = *(const bf16x8*)(wout + (size_t)(wn +      col)*256 + kc*32 + quad*8);
    bf16x8 bfr1 = *(const bf16x8*)(wout + (size_t)(wn + 16 + col)*256 + kc*32 + quad*8);
    #pragma unroll
    for (int mi=0;mi<4;mi++){
      bf16x8 af = *(const bf16x8*)&sy[mi*16 + col][kc*32 + quad*8];
      acc[mi][0] = __builtin_amdgcn_mfma_f32_16x16x32_bf16(af, bfr0, acc[mi][0], 0, 0, 0);
      acc[mi][1] = __builtin_amdgcn_mfma_f32_16x16x32_bf16(af, bfr1, acc[mi][1], 0, 0, 0);
    }
  }
  __syncthreads();   // sy reads done; sx may now overwrite

  // ---- epilogue: residual add -> (global,) LDS(sx) ----
  #pragma unroll
  for (int mi=0;mi<4;mi++){
    #pragma unroll
    for (int j=0;j<2;j++){
      int n = wn + j*16 + col;
      #pragma unroll
      for (int r=0;r<4;r++){
        int ml = mi*16 + quad*4 + r;
        size_t go = (m0 + ml)*DMODEL + n;
        float nx = xres[go] + acc[mi][j][r];
        if constexpr(!LAST) xres[go] = nx;
        sx[ml*132 + n] = nx;
      }
    }
  }
  __syncthreads();
  if constexpr(!LAST){
    // rms for next layer
    int row = tid >> 2, q = tid & 3;
    const float* pr = sx + row*132 + q*32;
    float ss = 0.f;
    #pragma unroll
    for (int i=0;i<32;i+=4){
      float4 v = *(const float4*)(pr + i);
      ss += v.x*v.x + v.y*v.y + v.z*v.z + v.w*v.w;
    }
    ss += __shfl_xor(ss, 1);
    ss += __shfl_xor(ss, 2);
    if (q == 0) rs[m0 + row] = rsqrtf(ss*(1.f/128.f) + 1e-5f);
  } else {
    // masked pool partial over this 64-token block
    float* pp = (float*)svbc;    // dead after scan phase
    int n = tid & 127, h = tid >> 7;
    float acc2 = 0.f;
    #pragma unroll 4
    for (int i=0;i<32;i++){
      int tl = h*32 + i;
      acc2 = fmaf(sx[tl*132 + n], mask[m0 + tl], acc2);
    }
    pp[h*128 + n] = acc2;
    __syncthreads();
    if (h == 0) part[((size_t)b*NSEG + g)*128 + n] = pp[n] + pp[128+n];
    if (tid == 0){
      float ms = 0.f;
      for (int t=0;t<SEG;t++) ms += mask[m0 + t];
      pmask[b*NSEG + g] = ms;
    }
  }
}

// ---------------- fused head: pool2 + mlp1 + mlp2 + mlp3 ----------------
__global__ __launch_bounds__(512) void k_head(const float* __restrict__ part,
    const float* __restrict__ pmask,
    const float* __restrict__ l1w, const float* __restrict__ l1b,
    const float* __restrict__ l2w, const float* __restrict__ l2b,
    const float* __restrict__ l3w, const float* __restrict__ l3b,
    float* __restrict__ out){
  __shared__ float sp[128];
  __shared__ float sh[512];
  int b = blockIdx.x, tid = threadIdx.x;
  if (tid < 128){
    float acc = 0.f, ms = 0.f;
    for (int s=0;s<32;s++){
      acc += part[((size_t)b*32+s)*128 + tid];
      ms  += pmask[b*32+s];
    }
    sp[tid] = acc / fmaxf(ms, 1e-9f);
  }
  __syncthreads();
  {
    const float4* pw = (const float4*)(l1w + (size_t)tid*128);
    const float4* pi = (const float4*)sp;
    float acc = 0.f;
    #pragma unroll 8
    for (int k=0;k<32;k++){
      float4 a = pi[k], w = pw[k];
      acc = fmaf(a.x,w.x, fmaf(a.y,w.y, fmaf(a.z,w.z, fmaf(a.w,w.w, acc))));
    }
    __syncthreads();
    sh[tid] = fmaxf(acc + l1b[tid], 0.f);
  }
  __syncthreads();
  float h2v;
  {
    const float4* pw = (const float4*)(l2w + (size_t)tid*512);
    const float4* pi = (const float4*)sh;
    float acc = 0.f;
    #pragma unroll 8
    for (int k=0;k<128;k++){
      float4 a = pi[k], w = pw[k];
      acc = fmaf(a.x,w.x, fmaf(a.y,w.y, fmaf(a.z,w.z, fmaf(a.w,w.w, acc))));
    }
    h2v = fmaxf(acc + l2b[tid], 0.f);
  }
  __syncthreads();
  sh[tid] = h2v;
  __syncthreads();
  if (tid < 192){
    int n = tid >> 6, lane = tid & 63;
    float acc = 0.f;
    for (int k=lane; k<512; k+=64) acc = fmaf(sh[k], l3w[(size_t)n*512+k], acc);
    #pragma unroll
    for (int m=1;m<64;m<<=1) acc += __shfl_xor(acc, m);
    if (lane == 0) out[(size_t)b*3 + n] = acc + l3b[n];
  }
}

// ---------------- launch ----------------
extern "C" void kernel_launch(void* const* d_in, const int* in_sizes, int n_in,
                              void* d_out, int out_size, void* d_ws, size_t ws_size,
                              hipStream_t stream){
  const int*   tokens = (const int*)  d_in[0];
  const float* mask   = (const float*)d_in[1];
  const float* emb    = (const float*)d_in[2];
  const float* bn_w   = (const float*)d_in[3];
  const float* bn_b   = (const float*)d_in[4];
  const float* conv_w = (const float*)d_in[5];
  const float* conv_b = (const float*)d_in[6];
  const float* in_w   = (const float*)d_in[7];
  const float* c1_w   = (const float*)d_in[8];
  const float* c1_b   = (const float*)d_in[9];
  const float* xp_w   = (const float*)d_in[10];
  const float* dtp_w  = (const float*)d_in[11];
  const float* dtp_b  = (const float*)d_in[12];
  const float* A_log  = (const float*)d_in[13];
  const float* D_par  = (const float*)d_in[14];
  const float* out_w  = (const float*)d_in[15];
  const float* nrm_w  = (const float*)d_in[16];
  const float* l1w = (const float*)d_in[17]; const float* l1b = (const float*)d_in[18];
  const float* l2w = (const float*)d_in[19]; const float* l2b = (const float*)d_in[20];
  const float* l3w = (const float*)d_in[21]; const float* l3b = (const float*)d_in[22];
  float* dout = (float*)d_out;

  // per-token floats: x 128 + rs 1 + xi(bf16) 128 + dub(uint) 256 + vbc 32 + cseg 64
  //                   + sdt 4 + gz(bf16) 128 = 741
  int CB = 64;
  while (CB > 1 && ((size_t)CB*SL*741 + FIX_END)*4 > ws_size) CB >>= 1;
  if (((size_t)CB*SL*741 + FIX_END)*4 > ws_size) return;
  const size_t CTOK = (size_t)CB*SL;

  float* ws  = (float*)d_ws;
  float* pl  = ws + FIX_PL;
  float* pm  = ws + FIX_PM;
  __bf16* wpb   = (__bf16*)(ws + FIX_WP);
  __bf16* w2b   = (__bf16*)(ws + FIX_W2B);
  __bf16* winb  = (__bf16*)(ws + FIX_WINB);
  __bf16* woutb = (__bf16*)(ws + FIX_WOUTB);
  float* xcb = ws + FIX_END;                 // CTOK*128 fp32 residual x
  float* rs  = xcb + CTOK*128;               // CTOK
  __bf16* xib = (__bf16*)(rs + CTOK);        // CTOK*256 bf16 (x-branch)
  unsigned int* dub = (unsigned int*)(xib + CTOK*256);   // CTOK*256 uint (packed dt,u)
  float* vbc = (float*)(dub + CTOK*256);     // CTOK*32 fp32 (B then C)
  float* csg = vbc + CTOK*32;                // CTOK*64
  float* sdt = csg + CTOK*64;                // CTOK*4
  __bf16* zb  = (__bf16*)(sdt + CTOK*4);     // CTOK*256 bf16 (gz)

  k_prep<<<1984, 256, 0, stream>>>(conv_w, w2b, in_w, winb, out_w, woutb, xp_w, wpb);

  const int nchunks = NB / CB;
  for (int c = 0; c < nchunks; c++){
    const int* tok_c = tokens + (size_t)c*CTOK;
    const float* mask_c = mask + (size_t)c*CTOK;

    k_mgemm<0,384,128><<<dim3(1, CTOK/128), 256, 0, stream>>>(
        tok_c, w2b, conv_b, emb, bn_w, bn_b, xcb, nullptr, nullptr, rs);

    for (int layer = 0; layer < NLAYER; layer++){
      const __bf16* lin = winb  + (size_t)layer*512*128;
      const float* lcw  = c1_w  + (size_t)layer*DIN*4;
      const float* lcb  = c1_b  + (size_t)layer*DIN;
      const float* ldw  = dtp_w + (size_t)layer*DIN*8;
      const float* ldb  = dtp_b + (size_t)layer*DIN;
      const float* lal  = A_log + (size_t)layer*DIN*DST;
      const float* lD   = D_par + (size_t)layer*DIN;
      const __bf16* low = woutb + (size_t)layer*128*256;
      const float* lnw  = nrm_w + (size_t)layer*128;

      k_mgemm<1,128,512><<<dim3(4, CTOK/128), 256, 0, stream>>>(
          xcb, lin, nullptr, rs, lnw, nullptr, nullptr, xib, zb, nullptr);
      k_seg<<<(int)(CTOK/64), 256, 0, stream>>>(
          xib, wpb + (size_t)layer*64*256, lcw, lcb, ldw, ldb, lal, vbc, dub, csg, sdt);
      k_scanB<<<CB*16, 256, 0, stream>>>(csg, sdt, lal);
      if (layer < NLAYER-1){
        k_scanC3<0><<<(int)(CTOK/64), 256, 0, stream>>>(
            xcb, dub, vbc, zb, lal, lD, csg, low, rs, nullptr, nullptr, nullptr);
      } else {
        k_scanC3<1><<<(int)(CTOK/64), 256, 0, stream>>>(
            xcb, dub, vbc, zb, lal, lD, csg, low, rs,
            mask_c, pl + (size_t)c*CB*32*128, pm + (size_t)c*CB*32);
      }
    }
  }

  k_head<<<NB, 512, 0, stream>>>(pl, pm, l1w, l1b, l2w, l2b, l3w, l3b, dout);
}